// Round 3
// baseline (257.687 us; speedup 1.0000x reference)
//
#include <hip/hip_runtime.h>
#include <float.h>
#include <math.h>

// AdvancedLossFunction: total = 1.0*occ + 0.1*smooth + 0.01*sparse + 0.1*cons
// 3-NN via threshold-pruned brute force:
//   t(i,j) = d2(i,j) - |p_i|^2 = -2 p_i.q_j + |q_j|^2  (monotone in d2 for fixed i)
//   pass A: thresh_i = 3rd-smallest t over a 2048-point strided sample (upper bound:
//           any j with t > thresh_i is dominated by the 3 sample points)
//   pass B: full scan, insert only when t <= thresh_i  (~24 hits per i -> 9% wave-any)
// Same fmaf chain in both passes -> bit-identical t -> exact threshold semantics.

constexpr int   N_ = 16384;
constexpr int   F_ = 64;
constexpr float OCC_W = 1.0f, SMOOTH_W = 0.1f, SPARSE_W = 0.01f, CONS_W = 0.1f;
constexpr float EPS_ = 1e-7f;

// ws layout:
//   0          : float acc[4] {occ, cons, sparse, smooth}
//   16         : unsigned done
//   256        : float4 tj[N]      (-2x, -2y, -2z, |q|^2)
//   256+N*16   : float thresh[N]
//   +N*4       : float2 cand[CHUNKS*3][N]  (t, pred_of_neighbor)

__device__ __forceinline__ float tdist(float px, float py, float pz, float4 q) {
  return fmaf(px, q.x, fmaf(py, q.y, fmaf(pz, q.z, q.w)));
}

__global__ void reduce_tj_kernel(const float* __restrict__ pred,
                                 const float* __restrict__ targ,
                                 const float* __restrict__ feat,
                                 const float* __restrict__ pts,
                                 float* __restrict__ acc,
                                 float4* __restrict__ tj) {
  int tid = blockIdx.x * 256 + threadIdx.x;        // grid 256 -> 65536 threads
  float s_sp = 0.f;
  const float4* f4 = (const float4*)feat;
#pragma unroll
  for (int t = tid; t < N_ * F_ / 4; t += 65536) { // 4 iters
    float4 v = f4[t];
    s_sp += fabsf(v.x) + fabsf(v.y) + fabsf(v.z) + fabsf(v.w);
  }
  float s_occ = 0.f, s_cons = 0.f;
  if (tid < N_) {
    float pr = pred[tid];
    float tg = targ[tid];
    float p  = fminf(fmaxf(pr, EPS_), 1.0f - EPS_);
    s_occ = -(tg * logf(p) + (1.0f - tg) * log1pf(-p));
    float d = pr - tg;
    s_cons = d * d;
    float x = pts[3 * tid], y = pts[3 * tid + 1], z = pts[3 * tid + 2];
    tj[tid] = make_float4(-2.f * x, -2.f * y, -2.f * z,
                          fmaf(x, x, fmaf(y, y, z * z)));
  }
  for (int off = 32; off > 0; off >>= 1) {
    s_sp   += __shfl_down(s_sp, off);
    s_occ  += __shfl_down(s_occ, off);
    s_cons += __shfl_down(s_cons, off);
  }
  if ((threadIdx.x & 63) == 0) {
    atomicAdd(&acc[0], s_occ);
    atomicAdd(&acc[1], s_cons);
    atomicAdd(&acc[2], s_sp);
  }
}

// thresh_i = 3rd-smallest t over sample {j = i + 1 + 4096*sub + 8*s}, sub=0..3, s=0..511
// offsets are ==1 mod 8, never 0 mod N -> never self.
__global__ __launch_bounds__(256) void sample_kernel(const float4* __restrict__ tj,
                                                     float* __restrict__ thresh) {
  __shared__ float sh[256 * 3];
  int gtid = blockIdx.x * 256 + threadIdx.x;       // grid 256 -> 65536 threads
  int i   = gtid >> 2;
  int sub = gtid & 3;
  float4 ti = tj[i];
  float px = -0.5f * ti.x, py = -0.5f * ti.y, pz = -0.5f * ti.z;
  float b0 = FLT_MAX, b1 = FLT_MAX, b2 = FLT_MAX;
  int j = (i + 1 + 4096 * sub) & (N_ - 1);
#pragma unroll 4
  for (int s = 0; s < 512; ++s) {
    float4 q = tj[j];
    float t = tdist(px, py, pz, q);
    float nb0 = fminf(b0, t);
    float nb1 = fminf(b1, fmaxf(b0, t));
    float nb2 = fminf(b2, fmaxf(b1, t));
    b0 = nb0; b1 = nb1; b2 = nb2;
    j = (j + 8) & (N_ - 1);
  }
  sh[threadIdx.x * 3 + 0] = b0;
  sh[threadIdx.x * 3 + 1] = b1;
  sh[threadIdx.x * 3 + 2] = b2;
  __syncthreads();
  if (sub == 0) {
    float c0 = FLT_MAX, c1 = FLT_MAX, c2 = FLT_MAX;
    int base = threadIdx.x * 3;
#pragma unroll
    for (int u = 0; u < 12; ++u) {
      float t = sh[base + u];
      float n0 = fminf(c0, t);
      float n1 = fminf(c1, fmaxf(c0, t));
      float n2 = fminf(c2, fmaxf(c1, t));
      c0 = n0; c1 = n1; c2 = n2;
    }
    thresh[i] = c2;
  }
}

template <int CHUNKS>
__global__ __launch_bounds__(256) void knn_kernel(const float4* __restrict__ tj,
                                                  const float* __restrict__ pred,
                                                  const float* __restrict__ thresh,
                                                  float2* __restrict__ cand) {
  constexpr int CHUNK   = N_ / CHUNKS;
  constexpr int ITEMS   = 4;
  constexpr int IPG     = 1024;
  constexpr int IGROUPS = N_ / IPG;                // 16
  constexpr int TILE    = (CHUNK < 1024) ? CHUNK : 1024;

  int igrp  = blockIdx.x % IGROUPS;
  int chunk = blockIdx.x / IGROUPS;
  int j0    = chunk * CHUNK;

  __shared__ float4 tile[TILE];

  int   idx[ITEMS];
  float px[ITEMS], py[ITEMS], pz[ITEMS], th[ITEMS];
  float b0[ITEMS], b1[ITEMS], b2[ITEMS];
  float q0[ITEMS], q1[ITEMS], q2[ITEMS];
#pragma unroll
  for (int k = 0; k < ITEMS; ++k) {
    int i = igrp * IPG + threadIdx.x + k * 256;
    idx[k] = i;
    float4 ti = tj[i];
    px[k] = -0.5f * ti.x; py[k] = -0.5f * ti.y; pz[k] = -0.5f * ti.z;
    th[k] = thresh[i];
    b0[k] = b1[k] = b2[k] = FLT_MAX;
    q0[k] = q1[k] = q2[k] = 0.f;
  }

  for (int sub = 0; sub < CHUNK; sub += TILE) {
    __syncthreads();
    for (int t = threadIdx.x; t < TILE; t += 256)
      tile[t] = tj[j0 + sub + t];
    __syncthreads();
    int jg0 = j0 + sub;
#pragma unroll 4
    for (int jj = 0; jj < TILE; ++jj) {
      float4 c4 = tile[jj];                        // wave-uniform -> LDS broadcast
      int jg = jg0 + jj;
#pragma unroll
      for (int k = 0; k < ITEMS; ++k) {
        float t = tdist(px[k], py[k], pz[k], c4);
        if (t <= th[k]) {                          // ~9% wave-any
          if (jg != idx[k]) {
            float qw = pred[jg];
            bool cc0 = t < b0[k], cc1 = t < b1[k], cc2 = t < b2[k];
            if (cc2) {
              float nb2 = cc1 ? b1[k] : t;                     float nq2 = cc1 ? q1[k] : qw;
              float nb1 = cc0 ? b0[k] : (cc1 ? t : b1[k]);     float nq1 = cc0 ? q0[k] : (cc1 ? qw : q1[k]);
              float nb0 = cc0 ? t : b0[k];                     float nq0 = cc0 ? qw : q0[k];
              b0[k] = nb0; b1[k] = nb1; b2[k] = nb2;
              q0[k] = nq0; q1[k] = nq1; q2[k] = nq2;
            }
          }
        }
      }
    }
  }

#pragma unroll
  for (int k = 0; k < ITEMS; ++k) {
    cand[((size_t)chunk * 3 + 0) * N_ + idx[k]] = make_float2(b0[k], q0[k]);
    cand[((size_t)chunk * 3 + 1) * N_ + idx[k]] = make_float2(b1[k], q1[k]);
    cand[((size_t)chunk * 3 + 2) * N_ + idx[k]] = make_float2(b2[k], q2[k]);
  }
}

// 4 threads per i, chunks/4 each; LDS merge of 4 partial top-3s; ticket finalize.
__global__ __launch_bounds__(256) void merge_finalize_kernel(const float* __restrict__ pred,
                                                             const float2* __restrict__ cand,
                                                             int chunks,
                                                             float* __restrict__ acc,
                                                             unsigned* __restrict__ done,
                                                             float* __restrict__ out) {
  __shared__ float2 sh[256 * 3];
  __shared__ float wsum[4];
  int i_local = threadIdx.x >> 2, sub = threadIdx.x & 3;
  int i = blockIdx.x * 64 + i_local;               // grid 256 -> 64 i's per block
  int cpt = chunks >> 2;

  float b0 = FLT_MAX, b1 = FLT_MAX, b2 = FLT_MAX;
  float q0 = 0.f, q1 = 0.f, q2 = 0.f;
  for (int cc = 0; cc < cpt; ++cc) {
    int c = sub * cpt + cc;
    const float2* base = cand + (size_t)c * 3 * N_;
#pragma unroll
    for (int m = 0; m < 3; ++m) {
      float2 v = base[(size_t)m * N_ + i];
      float t = v.x, qw = v.y;
      if (t < b2) {
        bool cc0 = t < b0, cc1 = t < b1;
        float nb2 = cc1 ? b1 : t;                 float nq2 = cc1 ? q1 : qw;
        float nb1 = cc0 ? b0 : (cc1 ? t : b1);    float nq1 = cc0 ? q0 : (cc1 ? qw : q1);
        float nb0 = cc0 ? t : b0;                 float nq0 = cc0 ? qw : q0;
        b0 = nb0; b1 = nb1; b2 = nb2; q0 = nq0; q1 = nq1; q2 = nq2;
      }
    }
  }
  sh[threadIdx.x * 3 + 0] = make_float2(b0, q0);
  sh[threadIdx.x * 3 + 1] = make_float2(b1, q1);
  sh[threadIdx.x * 3 + 2] = make_float2(b2, q2);
  __syncthreads();

  float s = 0.f;
  if (sub == 0) {
    float c0 = FLT_MAX, c1 = FLT_MAX, c2 = FLT_MAX;
    float p0 = 0.f, p1 = 0.f, p2 = 0.f;
    int base = threadIdx.x * 3;
#pragma unroll
    for (int u = 0; u < 12; ++u) {
      float2 v = sh[base + u];
      float t = v.x, qw = v.y;
      if (t < c2) {
        bool cc0 = t < c0, cc1 = t < c1;
        float nb2 = cc1 ? c1 : t;                 float nq2 = cc1 ? p1 : qw;
        float nb1 = cc0 ? c0 : (cc1 ? t : c1);    float nq1 = cc0 ? p0 : (cc1 ? qw : p1);
        float nb0 = cc0 ? t : c0;                 float nq0 = cc0 ? qw : p0;
        c0 = nb0; c1 = nb1; c2 = nb2; p0 = nq0; p1 = nq1; p2 = nq2;
      }
    }
    float pi = pred[i];
    s = fabsf(pi - p0) + fabsf(pi - p1) + fabsf(pi - p2);
  }

  for (int off = 32; off > 0; off >>= 1) s += __shfl_down(s, off);
  if ((threadIdx.x & 63) == 0) wsum[threadIdx.x >> 6] = s;
  __syncthreads();

  if (threadIdx.x == 0) {
    float blocksum = wsum[0] + wsum[1] + wsum[2] + wsum[3];
    atomicAdd(&acc[3], blocksum);
    __threadfence();
    unsigned prev = atomicAdd(done, 1u);
    if (prev == (unsigned)(gridDim.x - 1)) {
      float occ  = atomicAdd(&acc[0], 0.f);
      float cons = atomicAdd(&acc[1], 0.f);
      float sp   = atomicAdd(&acc[2], 0.f);
      float sm   = atomicAdd(&acc[3], 0.f);
      out[0] = OCC_W * (occ / (float)N_)
             + CONS_W * (cons / (float)N_)
             + SPARSE_W * (sp / (float)(N_ * F_))
             + SMOOTH_W * (sm / (float)(N_ * 3));
    }
  }
}

extern "C" void kernel_launch(void* const* d_in, const int* in_sizes, int n_in,
                              void* d_out, int out_size, void* d_ws, size_t ws_size,
                              hipStream_t stream) {
  const float* pred = (const float*)d_in[0];
  const float* targ = (const float*)d_in[1];
  const float* feat = (const float*)d_in[2];
  const float* pts  = (const float*)d_in[3];
  float* out = (float*)d_out;

  char*     ws     = (char*)d_ws;
  float*    acc    = (float*)ws;
  unsigned* done   = (unsigned*)(ws + 16);
  float4*   tj     = (float4*)(ws + 256);
  float*    thresh = (float*)(ws + 256 + (size_t)N_ * 16);
  float2*   cand   = (float2*)(ws + 256 + (size_t)N_ * 16 + (size_t)N_ * 4);

  hipMemsetAsync(ws, 0, 256, stream);

  reduce_tj_kernel<<<256, 256, 0, stream>>>(pred, targ, feat, pts, acc, tj);
  sample_kernel<<<256, 256, 0, stream>>>(tj, thresh);

  size_t base = 256 + (size_t)N_ * 16 + (size_t)N_ * 4;
  auto need = [&](int c) { return base + (size_t)c * 3 * N_ * sizeof(float2); };
  int chunks;
  if      (ws_size >= need(64)) chunks = 64;
  else if (ws_size >= need(32)) chunks = 32;
  else if (ws_size >= need(16)) chunks = 16;
  else                          chunks = 4;

  if (chunks == 64)      knn_kernel<64><<<16 * 64, 256, 0, stream>>>(tj, pred, thresh, cand);
  else if (chunks == 32) knn_kernel<32><<<16 * 32, 256, 0, stream>>>(tj, pred, thresh, cand);
  else if (chunks == 16) knn_kernel<16><<<16 * 16, 256, 0, stream>>>(tj, pred, thresh, cand);
  else                   knn_kernel<4><<<16 * 4, 256, 0, stream>>>(tj, pred, thresh, cand);

  merge_finalize_kernel<<<256, 256, 0, stream>>>(pred, cand, chunks, acc, done, out);
}

// Round 4
// 210.097 us; speedup vs baseline: 1.2265x; 1.2265x over previous
//
#include <hip/hip_runtime.h>
#include <float.h>
#include <math.h>

// AdvancedLossFunction: total = 1.0*occ + 0.1*smooth + 0.01*sparse + 0.1*cons
// 3-NN via threshold-pruned brute force:
//   t(i,j) = d2(i,j) - |p_i|^2 = -2 p_i.q_j + |q_j|^2  (monotone in d2 for fixed i)
//   pass A (sample): thresh_i = 3rd-smallest t over the 2048 j's with j==i+1 (mod 8)
//   pass B (knn):    full scan, insert only when t <= thresh_i (~24 hits/i -> rare branch)
// Same fmaf chain in both passes -> bit-identical t -> exact threshold semantics.

constexpr int   N_ = 16384;
constexpr int   F_ = 64;
constexpr float OCC_W = 1.0f, SMOOTH_W = 0.1f, SPARSE_W = 0.01f, CONS_W = 0.1f;
constexpr float EPS_ = 1e-7f;

// ws layout:
//   0          : float acc[4] {occ, cons, sparse, smooth}
//   16         : unsigned done
//   256        : float4 tj[N]      (-2x, -2y, -2z, |q|^2)
//   256+N*16   : float thresh[N]
//   +N*4       : float2 cand[CHUNKS*3][N]  (t, pred_of_neighbor)

__device__ __forceinline__ float tdist(float px, float py, float pz, float4 q) {
  return fmaf(px, q.x, fmaf(py, q.y, fmaf(pz, q.z, q.w)));
}

__global__ __launch_bounds__(256) void reduce_tj_kernel(const float* __restrict__ pred,
                                                        const float* __restrict__ targ,
                                                        const float* __restrict__ feat,
                                                        const float* __restrict__ pts,
                                                        float* __restrict__ acc,
                                                        float4* __restrict__ tj) {
  int tid = blockIdx.x * 256 + threadIdx.x;        // grid 256 -> 65536 threads
  float s_sp = 0.f;
  const float4* f4 = (const float4*)feat;
#pragma unroll
  for (int t = tid; t < N_ * F_ / 4; t += 65536) { // 4 iters, coalesced
    float4 v = f4[t];
    s_sp += fabsf(v.x) + fabsf(v.y) + fabsf(v.z) + fabsf(v.w);
  }
  float s_occ = 0.f, s_cons = 0.f;
  if (tid < N_) {
    float pr = pred[tid];
    float tg = targ[tid];
    float p  = fminf(fmaxf(pr, EPS_), 1.0f - EPS_);
    s_occ = -(tg * __logf(p) + (1.0f - tg) * __logf(1.0f - p));
    float d = pr - tg;
    s_cons = d * d;
    float x = pts[3 * tid], y = pts[3 * tid + 1], z = pts[3 * tid + 2];
    tj[tid] = make_float4(-2.f * x, -2.f * y, -2.f * z,
                          fmaf(x, x, fmaf(y, y, z * z)));
  }
  for (int off = 32; off > 0; off >>= 1) {
    s_sp   += __shfl_down(s_sp, off);
    s_occ  += __shfl_down(s_occ, off);
    s_cons += __shfl_down(s_cons, off);
  }
  if ((threadIdx.x & 63) == 0) {
    atomicAdd(&acc[0], s_occ);
    atomicAdd(&acc[1], s_cons);
    atomicAdd(&acc[2], s_sp);
  }
}

// thresh_i = 3rd-smallest t over {j = (i + 1 + 8k) mod N, k=0..2047}.
// 16 threads per i (sub=0..15), 128 samples each; no loop-carried address dep.
__global__ __launch_bounds__(256) void sample_kernel(const float4* __restrict__ tj,
                                                     float* __restrict__ thresh) {
  __shared__ float sh[256 * 3];
  int i_local = threadIdx.x & 15;
  int sub     = threadIdx.x >> 4;                  // 0..15
  int i = blockIdx.x * 16 + i_local;               // grid 1024 -> 4 blocks/CU
  float4 ti = tj[i];
  float px = -0.5f * ti.x, py = -0.5f * ti.y, pz = -0.5f * ti.z;
  float b0 = FLT_MAX, b1 = FLT_MAX, b2 = FLT_MAX;
  int base = i + 1 + 1024 * sub;
#pragma unroll 8
  for (int s = 0; s < 128; ++s) {
    int j = (base + 8 * s) & (N_ - 1);             // independent per s -> ILP
    float4 q = tj[j];
    float t = tdist(px, py, pz, q);
    float n0 = fminf(b0, t);
    float n1 = fminf(b1, fmaxf(b0, t));
    float n2 = fminf(b2, fmaxf(b1, t));
    b0 = n0; b1 = n1; b2 = n2;
  }
  sh[threadIdx.x * 3 + 0] = b0;
  sh[threadIdx.x * 3 + 1] = b1;
  sh[threadIdx.x * 3 + 2] = b2;
  __syncthreads();
  if (threadIdx.x < 16) {
    float c0 = FLT_MAX, c1 = FLT_MAX, c2 = FLT_MAX;
#pragma unroll
    for (int u = 0; u < 16; ++u) {
      int b = (u * 16 + threadIdx.x) * 3;
#pragma unroll
      for (int m = 0; m < 3; ++m) {
        float t = sh[b + m];
        float n0 = fminf(c0, t);
        float n1 = fminf(c1, fmaxf(c0, t));
        float n2 = fminf(c2, fmaxf(c1, t));
        c0 = n0; c1 = n1; c2 = n2;
      }
    }
    thresh[blockIdx.x * 16 + threadIdx.x] = c2;
  }
}

template <int CHUNKS>
__global__ __launch_bounds__(256) void knn_kernel(const float4* __restrict__ tj,
                                                  const float* __restrict__ pred,
                                                  const float* __restrict__ thresh,
                                                  float2* __restrict__ cand) {
  constexpr int CHUNK   = N_ / CHUNKS;
  constexpr int ITEMS   = 4;
  constexpr int IPG     = 1024;
  constexpr int IGROUPS = N_ / IPG;                // 16
  constexpr int TILE    = (CHUNK < 1024) ? CHUNK : 1024;

  int igrp  = blockIdx.x % IGROUPS;
  int chunk = blockIdx.x / IGROUPS;
  int j0    = chunk * CHUNK;

  __shared__ float4 tile[TILE];
  __shared__ float  tilep[TILE];

  int   idx[ITEMS];
  float px[ITEMS], py[ITEMS], pz[ITEMS], th[ITEMS];
  float b0[ITEMS], b1[ITEMS], b2[ITEMS];
  float q0[ITEMS], q1[ITEMS], q2[ITEMS];
#pragma unroll
  for (int k = 0; k < ITEMS; ++k) {
    int i = igrp * IPG + threadIdx.x + k * 256;
    idx[k] = i;
    float4 ti = tj[i];
    px[k] = -0.5f * ti.x; py[k] = -0.5f * ti.y; pz[k] = -0.5f * ti.z;
    th[k] = thresh[i];
    b0[k] = b1[k] = b2[k] = FLT_MAX;
    q0[k] = q1[k] = q2[k] = 0.f;
  }

  for (int sub = 0; sub < CHUNK; sub += TILE) {
    __syncthreads();
    for (int t = threadIdx.x; t < TILE; t += 256) {
      tile[t]  = tj[j0 + sub + t];
      tilep[t] = pred[j0 + sub + t];
    }
    __syncthreads();
    int jg0 = j0 + sub;
#pragma unroll 4
    for (int jj = 0; jj < TILE; ++jj) {
      float4 c4 = tile[jj];                        // wave-uniform -> LDS broadcast
      int jg = jg0 + jj;
#pragma unroll
      for (int k = 0; k < ITEMS; ++k) {
        float t = tdist(px[k], py[k], pz[k], c4);
        if (t <= th[k]) {                          // rare
          if (jg != idx[k]) {
            float qw = tilep[jj];                  // LDS, only on insert
            bool cc0 = t < b0[k], cc1 = t < b1[k], cc2 = t < b2[k];
            if (cc2) {
              float nb2 = cc1 ? b1[k] : t;                     float nq2 = cc1 ? q1[k] : qw;
              float nb1 = cc0 ? b0[k] : (cc1 ? t : b1[k]);     float nq1 = cc0 ? q0[k] : (cc1 ? qw : q1[k]);
              float nb0 = cc0 ? t : b0[k];                     float nq0 = cc0 ? qw : q0[k];
              b0[k] = nb0; b1[k] = nb1; b2[k] = nb2;
              q0[k] = nq0; q1[k] = nq1; q2[k] = nq2;
            }
          }
        }
      }
    }
  }

#pragma unroll
  for (int k = 0; k < ITEMS; ++k) {
    cand[((size_t)chunk * 3 + 0) * N_ + idx[k]] = make_float2(b0[k], q0[k]);
    cand[((size_t)chunk * 3 + 1) * N_ + idx[k]] = make_float2(b1[k], q1[k]);
    cand[((size_t)chunk * 3 + 2) * N_ + idx[k]] = make_float2(b2[k], q2[k]);
  }
}

// 8 threads per i (chunk-strided), 32 i's per block, grid 512; LDS merge; ticket finalize.
__global__ __launch_bounds__(256) void merge_finalize_kernel(const float* __restrict__ pred,
                                                             const float2* __restrict__ cand,
                                                             int chunks,
                                                             float* __restrict__ acc,
                                                             unsigned* __restrict__ done,
                                                             float* __restrict__ out) {
  __shared__ float2 sh[256 * 3];
  int i_local = threadIdx.x & 31;
  int sub     = threadIdx.x >> 5;                  // 0..7
  int i = blockIdx.x * 32 + i_local;               // grid 512

  float b0 = FLT_MAX, b1 = FLT_MAX, b2 = FLT_MAX;
  float q0 = 0.f, q1 = 0.f, q2 = 0.f;
  for (int c = sub; c < chunks; c += 8) {
    const float2* base = cand + (size_t)c * 3 * N_;
#pragma unroll
    for (int m = 0; m < 3; ++m) {
      float2 v = base[(size_t)m * N_ + i];         // lanes: 32 consecutive i -> 256B
      float t = v.x, qw = v.y;
      if (t < b2) {
        bool cc0 = t < b0, cc1 = t < b1;
        float nb2 = cc1 ? b1 : t;                 float nq2 = cc1 ? q1 : qw;
        float nb1 = cc0 ? b0 : (cc1 ? t : b1);    float nq1 = cc0 ? q0 : (cc1 ? qw : q1);
        float nb0 = cc0 ? t : b0;                 float nq0 = cc0 ? qw : q0;
        b0 = nb0; b1 = nb1; b2 = nb2; q0 = nq0; q1 = nq1; q2 = nq2;
      }
    }
  }
  sh[threadIdx.x * 3 + 0] = make_float2(b0, q0);
  sh[threadIdx.x * 3 + 1] = make_float2(b1, q1);
  sh[threadIdx.x * 3 + 2] = make_float2(b2, q2);
  __syncthreads();

  float s = 0.f;
  if (threadIdx.x < 32) {
    float c0 = FLT_MAX, c1 = FLT_MAX, c2 = FLT_MAX;
    float p0 = 0.f, p1 = 0.f, p2 = 0.f;
#pragma unroll
    for (int u = 0; u < 8; ++u) {
      int b = (u * 32 + threadIdx.x) * 3;
#pragma unroll
      for (int m = 0; m < 3; ++m) {
        float2 v = sh[b + m];
        float t = v.x, qw = v.y;
        if (t < c2) {
          bool cc0 = t < c0, cc1 = t < c1;
          float nb2 = cc1 ? c1 : t;                 float nq2 = cc1 ? p1 : qw;
          float nb1 = cc0 ? c0 : (cc1 ? t : c1);    float nq1 = cc0 ? p0 : (cc1 ? qw : p1);
          float nb0 = cc0 ? t : c0;                 float nq0 = cc0 ? qw : p0;
          c0 = nb0; c1 = nb1; c2 = nb2; p0 = nq0; p1 = nq1; p2 = nq2;
        }
      }
    }
    float pi = pred[blockIdx.x * 32 + threadIdx.x];
    s = fabsf(pi - p0) + fabsf(pi - p1) + fabsf(pi - p2);
  }

  if (threadIdx.x < 64) {                          // wave 0 only
    for (int off = 32; off > 0; off >>= 1) s += __shfl_down(s, off);
    if (threadIdx.x == 0) {
      atomicAdd(&acc[3], s);
      __threadfence();
      unsigned prev = atomicAdd(done, 1u);
      if (prev == (unsigned)(gridDim.x - 1)) {
        float occ  = atomicAdd(&acc[0], 0.f);
        float cons = atomicAdd(&acc[1], 0.f);
        float sp   = atomicAdd(&acc[2], 0.f);
        float sm   = atomicAdd(&acc[3], 0.f);
        out[0] = OCC_W * (occ / (float)N_)
               + CONS_W * (cons / (float)N_)
               + SPARSE_W * (sp / (float)(N_ * F_))
               + SMOOTH_W * (sm / (float)(N_ * 3));
      }
    }
  }
}

extern "C" void kernel_launch(void* const* d_in, const int* in_sizes, int n_in,
                              void* d_out, int out_size, void* d_ws, size_t ws_size,
                              hipStream_t stream) {
  const float* pred = (const float*)d_in[0];
  const float* targ = (const float*)d_in[1];
  const float* feat = (const float*)d_in[2];
  const float* pts  = (const float*)d_in[3];
  float* out = (float*)d_out;

  char*     ws     = (char*)d_ws;
  float*    acc    = (float*)ws;
  unsigned* done   = (unsigned*)(ws + 16);
  float4*   tj     = (float4*)(ws + 256);
  float*    thresh = (float*)(ws + 256 + (size_t)N_ * 16);
  float2*   cand   = (float2*)(ws + 256 + (size_t)N_ * 16 + (size_t)N_ * 4);

  hipMemsetAsync(ws, 0, 256, stream);

  reduce_tj_kernel<<<256, 256, 0, stream>>>(pred, targ, feat, pts, acc, tj);
  sample_kernel<<<1024, 256, 0, stream>>>(tj, thresh);

  size_t base = 256 + (size_t)N_ * 16 + (size_t)N_ * 4;
  auto need = [&](int c) { return base + (size_t)c * 3 * N_ * sizeof(float2); };
  int chunks;
  if      (ws_size >= need(128)) chunks = 128;
  else if (ws_size >= need(64))  chunks = 64;
  else if (ws_size >= need(32))  chunks = 32;
  else if (ws_size >= need(16))  chunks = 16;
  else                           chunks = 4;

  if (chunks == 128)     knn_kernel<128><<<16 * 128, 256, 0, stream>>>(tj, pred, thresh, cand);
  else if (chunks == 64) knn_kernel<64><<<16 * 64, 256, 0, stream>>>(tj, pred, thresh, cand);
  else if (chunks == 32) knn_kernel<32><<<16 * 32, 256, 0, stream>>>(tj, pred, thresh, cand);
  else if (chunks == 16) knn_kernel<16><<<16 * 16, 256, 0, stream>>>(tj, pred, thresh, cand);
  else                   knn_kernel<4><<<16 * 4, 256, 0, stream>>>(tj, pred, thresh, cand);

  merge_finalize_kernel<<<512, 256, 0, stream>>>(pred, cand, chunks, acc, done, out);
}